// Round 1
// 155.797 us; speedup vs baseline: 1.0708x; 1.0708x over previous
//
#include <hip/hip_runtime.h>

// Sinkhorn loss, single-pass moment formulation.
//   s_t = relu(v_t); X_t = cumsum(s); Sx = sum_t X_t
//   loss_p = sum_t t * (X_t/Sx - Y_t/Sy)^2 ;  out = sum_p loss_p
// Chunk j (LCH=64 rows; local cumsums L,M; exclusive offsets O,P):
//   sum_{t in j} t*(isx*X - isy*Y)^2 = g^2*T_j + 2g*(isx*pL - isy*pM)
//        + isx^2*pLL - 2*isx*isy*pLM + isy^2*pMM,  g = isx*O - isy*P.
// Evidence base (R1..R10 prev session): p1 delivered BW invariant ~3.2 TB/s
// across waves/CU {8,16,32} x width {4,8,16B} x contiguity x batching —
// hierarchy-mix ceiling (50% L3-hit / 50% HBM + moment writes). p1 untouched.
// R11 (this round): p2's 9 loads were 64-lane gathers at 16KB stride
// (64B line per 4B used, 2.36M requests). Rewritten: 16 cols/block,
// coalesced float4 tile staging into LDS (pad 17 -> 2-way bank alias = free),
// then the verified wave-per-column double shuffle-scan reads from LDS.

#define NT   4096
#define NP   4096
#define CH   64     // number of t-chunks == wave size
#define LCH  64     // chunk length; CH*LCH == NT
#define BLK  256

#define PCOLS 16    // columns per p2 block
#define PPAD  17    // LDS row stride (floats); odd -> conflict-free col reads

__global__ __launch_bounds__(BLK) void p1_moments(
    const float* __restrict__ x, const float* __restrict__ y,
    float* __restrict__ aX, float* __restrict__ aY,
    float* __restrict__ uL, float* __restrict__ uM,
    float* __restrict__ pL, float* __restrict__ pM,
    float* __restrict__ pLL, float* __restrict__ pMM,
    float* __restrict__ pLM)
{
  const int pv = blockIdx.x * BLK + threadIdx.x;  // 0 .. NP/2-1 (float2 col)
  const int j  = blockIdx.y;
  const int t0 = j * LCH;
  const float2* xb = (const float2*)x + (size_t)t0 * (NP / 2) + pv;
  const float2* yb = (const float2*)y + (size_t)t0 * (NP / 2) + pv;

  float cx0 = 0.f, cx1 = 0.f, cy0 = 0.f, cy1 = 0.f;
  float uL0 = 0.f, uL1 = 0.f, uM0 = 0.f, uM1 = 0.f;
  float pL0 = 0.f, pL1 = 0.f, pM0 = 0.f, pM1 = 0.f;
  float pLL0 = 0.f, pLL1 = 0.f, pMM0 = 0.f, pMM1 = 0.f;
  float pLM0 = 0.f, pLM1 = 0.f;

#pragma unroll 8
  for (int i = 0; i < LCH; ++i) {
    const float2 xv = xb[(size_t)i * (NP / 2)];
    const float2 yv = yb[(size_t)i * (NP / 2)];
    const float t = (float)(t0 + i);

    const float lx0 = fmaxf(xv.x, 0.f), lx1 = fmaxf(xv.y, 0.f);
    const float ly0 = fmaxf(yv.x, 0.f), ly1 = fmaxf(yv.y, 0.f);

    cx0 += lx0; cy0 += ly0;
    const float tl0 = t * cx0, tm0 = t * cy0;
    pL0  += tl0;                  pM0  += tm0;
    pLL0 = fmaf(tl0, cx0, pLL0);  pMM0 = fmaf(tm0, cy0, pMM0);
    pLM0 = fmaf(tl0, cy0, pLM0);
    uL0  += cx0;                  uM0  += cy0;

    cx1 += lx1; cy1 += ly1;
    const float tl1 = t * cx1, tm1 = t * cy1;
    pL1  += tl1;                  pM1  += tm1;
    pLL1 = fmaf(tl1, cx1, pLL1);  pMM1 = fmaf(tm1, cy1, pMM1);
    pLM1 = fmaf(tl1, cy1, pLM1);
    uL1  += cx1;                  uM1  += cy1;
  }

  const size_t o2 = (size_t)j * (NP / 2) + pv;
  ((float2*)aX)[o2]  = make_float2(cx0, cx1);
  ((float2*)aY)[o2]  = make_float2(cy0, cy1);
  ((float2*)uL)[o2]  = make_float2(uL0, uL1);
  ((float2*)uM)[o2]  = make_float2(uM0, uM1);
  ((float2*)pL)[o2]  = make_float2(pL0, pL1);
  ((float2*)pM)[o2]  = make_float2(pM0, pM1);
  ((float2*)pLL)[o2] = make_float2(pLL0, pLL1);
  ((float2*)pMM)[o2] = make_float2(pMM0, pMM1);
  ((float2*)pLM)[o2] = make_float2(pLM0, pLM1);
}

// p2: block owns PCOLS=16 columns. Stage nine [64][16] tiles coalesced
// (float4 rows, every 64B line fully used) into padded LDS, then each of the
// 4 waves runs the verified wave-per-column double shuffle-scan for 4 cols.
__global__ __launch_bounds__(BLK) void p2_loss(
    const float* __restrict__ aX, const float* __restrict__ aY,
    const float* __restrict__ uL, const float* __restrict__ uM,
    const float* __restrict__ pL, const float* __restrict__ pM,
    const float* __restrict__ pLL, const float* __restrict__ pMM,
    const float* __restrict__ pLM,
    double* __restrict__ part)
{
  __shared__ float s[9][CH][PPAD];   // 9*64*17*4 = 38.25 KB

  const int tid = threadIdx.x;
  const int p0  = blockIdx.x * PCOLS;

  // staging: tid -> (row j = tid>>2, float4 slot q = tid&3); one float4 per
  // array per thread. Wave covers 16 rows x 64B = fully-utilized lines.
  {
    const int j = tid >> 2;        // 0..63
    const int q = tid & 3;         // 0..3  (float4 within the 16-col row)
    const float* __restrict__ srcs[9] = {aX, aY, uL, uM, pL, pM, pLL, pMM, pLM};
#pragma unroll
    for (int a = 0; a < 9; ++a) {
      const float4 v = *(const float4*)(srcs[a] + (size_t)j * NP + p0 + 4 * q);
      s[a][j][4 * q + 0] = v.x;
      s[a][j][4 * q + 1] = v.y;
      s[a][j][4 * q + 2] = v.z;
      s[a][j][4 * q + 3] = v.w;
    }
  }
  __syncthreads();

  const int wave = tid >> 6;           // 4 waves per block
  const int lane = tid & 63;           // = chunk j

#pragma unroll
  for (int c = 0; c < 4; ++c) {
    const int col = wave * 4 + c;

    const double a  = (double)s[0][lane][col];
    const double b  = (double)s[1][lane][col];
    const double ul = (double)s[2][lane][col];
    const double um = (double)s[3][lane][col];

    // inclusive scan -> exclusive offsets
    double sx = a, sy = b;
    for (int d = 1; d < 64; d <<= 1) {
      const double tx = __shfl_up(sx, d, 64);
      const double ty = __shfl_up(sy, d, 64);
      if (lane >= d) { sx += tx; sy += ty; }
    }
    const double O = sx - a;
    const double P = sy - b;

    // Sx = sum_j (LCH*O_j + uL_j), butterfly reduce (all lanes get total)
    double vx = (double)LCH * O + ul;
    double vy = (double)LCH * P + um;
    for (int m = 32; m; m >>= 1) {
      vx += __shfl_xor(vx, m, 64);
      vy += __shfl_xor(vy, m, 64);
    }
    const double isx = 1.0 / vx;
    const double isy = 1.0 / vy;

    const double g   = isx * O - isy * P;
    const double Tj  = 4096.0 * (double)lane + 2016.0;
    const double sh  = isx * (double)s[4][lane][col] - isy * (double)s[5][lane][col];
    const double shh = isx * isx * (double)s[6][lane][col]
                     - 2.0 * isx * isy * (double)s[8][lane][col]
                     + isy * isy * (double)s[7][lane][col];
    double loss = g * g * Tj + 2.0 * g * sh + shh;

    for (int m = 32; m; m >>= 1) loss += __shfl_xor(loss, m, 64);
    if (lane == 0) part[p0 + col] = loss;
  }
}

__global__ __launch_bounds__(1024) void p3_final(
    const double* __restrict__ part, float* __restrict__ out)
{
  __shared__ double red[1024];
  double v = 0.0;
  for (int i = threadIdx.x; i < NP; i += 1024) v += part[i];
  red[threadIdx.x] = v;
  __syncthreads();
  for (int s = 512; s > 0; s >>= 1) {
    if (threadIdx.x < s) red[threadIdx.x] += red[threadIdx.x + s];
    __syncthreads();
  }
  if (threadIdx.x == 0) out[0] = (float)red[0];
}

extern "C" void kernel_launch(void* const* d_in, const int* in_sizes, int n_in,
                              void* d_out, int out_size, void* d_ws, size_t ws_size,
                              hipStream_t stream) {
  const float* x = (const float*)d_in[0];
  const float* y = (const float*)d_in[1];
  float* out = (float*)d_out;

  const size_t CNP = (size_t)CH * NP;
  char* ws = (char*)d_ws;
  float* aX  = (float*)ws; ws += CNP * sizeof(float);
  float* aY  = (float*)ws; ws += CNP * sizeof(float);
  float* uLp = (float*)ws; ws += CNP * sizeof(float);
  float* uMp = (float*)ws; ws += CNP * sizeof(float);
  float* pLp = (float*)ws; ws += CNP * sizeof(float);
  float* pMp = (float*)ws; ws += CNP * sizeof(float);
  float* pLLp = (float*)ws; ws += CNP * sizeof(float);
  float* pMMp = (float*)ws; ws += CNP * sizeof(float);
  float* pLMp = (float*)ws; ws += CNP * sizeof(float);
  double* part = (double*)ws; ws += (size_t)NP * sizeof(double);

  dim3 g1((NP / 2) / BLK, CH);  // 8 x 64 blocks, 2048 waves
  p1_moments<<<g1, BLK, 0, stream>>>(x, y, aX, aY, uLp, uMp, pLp, pMp, pLLp, pMMp, pLMp);
  p2_loss<<<NP / PCOLS, BLK, 0, stream>>>(aX, aY, uLp, uMp, pLp, pMp, pLLp, pMMp, pLMp, part);
  p3_final<<<1, 1024, 0, stream>>>(part, out);
}